// Round 8
// baseline (399.830 us; speedup 1.0000x reference)
//
#include <hip/hip_runtime.h>

#define D 64

typedef __attribute__((ext_vector_type(8))) short short8;
typedef __attribute__((ext_vector_type(4))) float f32x4;

__device__ __forceinline__ ushort f2b(float f) {
    union { float f; unsigned u; } x; x.f = f;
    unsigned r = x.u + 0x7FFFu + ((x.u >> 16) & 1u);   // RNE to bf16
    return (ushort)(r >> 16);
}
__device__ __forceinline__ float b2f(ushort u) {
    union { float f; unsigned u; } x; x.u = ((unsigned)u) << 16;
    return x.f;
}
__device__ __forceinline__ short8 pack8(float4 a, float4 b) {
    short8 r;
    r[0] = (short)f2b(a.x); r[1] = (short)f2b(a.y); r[2] = (short)f2b(a.z); r[3] = (short)f2b(a.w);
    r[4] = (short)f2b(b.x); r[5] = (short)f2b(b.y); r[6] = (short)f2b(b.z); r[7] = (short)f2b(b.w);
    return r;
}

// ---------------------------------------------------------------------------
// Setup: Wcomb_b[n*64+k] = bf16( (W_edge @ W_dense[0:64])[k][n] ),
// bias2 = b_dense + bias_edge.
// ---------------------------------------------------------------------------
__global__ __launch_bounds__(256) void setup_kernel(
    const float* __restrict__ W_edge, const float* __restrict__ W_dense,
    const float* __restrict__ b_dense, const float* __restrict__ bias_edge,
    ushort* __restrict__ Wcomb_b, float* __restrict__ bias2)
{
    const int tid = threadIdx.x;
    for (int idx = tid; idx < D * D; idx += 256) {
        int k = idx >> 6, n = idx & 63;
        float s = 0.f;
        #pragma unroll 8
        for (int j = 0; j < D; ++j)
            s = fmaf(W_edge[k * D + j], W_dense[j * D + n], s);
        Wcomb_b[n * D + k] = f2b(s);   // B-fragment layout [n][k]
    }
    if (tid < D) bias2[tid] = b_dense[tid] + bias_edge[tid];
}

// ---------------------------------------------------------------------------
// Kernel 1 (fused): nf_out = relu(nf @ W_node + bias_node)  (f32, exact)
//                   nfp_b  = bf16( nf_out @ (0.5 * W_dense[64:128]) )
// ---------------------------------------------------------------------------
__global__ __launch_bounds__(256) void node_proj_kernel(
    const float* __restrict__ nf, const float* __restrict__ Wn,
    const float* __restrict__ bias, const float* __restrict__ Wd_bot,
    float* __restrict__ out, ushort* __restrict__ nfp_b, int N)
{
    constexpr int ROWS = 16;
    __shared__ float Ws[D * D];
    __shared__ float Wb[D * D];
    __shared__ float As[ROWS * D];
    __shared__ float Vs[ROWS * D];
    const int tid = threadIdx.x;
    const long row0 = (long)blockIdx.x * ROWS;

    #pragma unroll
    for (int i = tid; i < D * D / 4; i += 256) {
        ((float4*)Ws)[i] = ((const float4*)Wn)[i];
        float4 v = ((const float4*)Wd_bot)[i];
        ((float4*)Wb)[i] = make_float4(0.5f * v.x, 0.5f * v.y, 0.5f * v.z, 0.5f * v.w);
    }
    {
        int i = tid;  // ROWS*D/4 == 256
        long r = row0 + (i * 4) / D;
        ((float4*)As)[i] = (r < N) ? ((const float4*)nf)[row0 * D / 4 + i]
                                   : make_float4(0.f, 0.f, 0.f, 0.f);
    }
    __syncthreads();

    const int c = tid & 63;
    const float b = bias[c];
    for (int rr = tid >> 6; rr < ROWS; rr += 4) {
        float acc = 0.f;
        #pragma unroll
        for (int k = 0; k < D; ++k)
            acc = fmaf(As[rr * D + k], Ws[k * D + c], acc);
        float v = fmaxf(acc + b, 0.f);
        Vs[rr * D + c] = v;
        long r = row0 + rr;
        if (r < N) out[r * D + c] = v;
    }
    __syncthreads();
    for (int rr = tid >> 6; rr < ROWS; rr += 4) {
        float acc = 0.f;
        #pragma unroll
        for (int k = 0; k < D; ++k)
            acc = fmaf(Vs[rr * D + k], Wb[k * D + c], acc);
        long r = row0 + rr;
        if (r < N) nfp_b[r * D + c] = f2b(acc);
    }
}

// ---------------------------------------------------------------------------
// Counting sort of edges by dst: hist -> scan (3 stages) -> scatter (eid,dst)
// ---------------------------------------------------------------------------
__global__ __launch_bounds__(256) void hist_kernel(
    const int* __restrict__ dst, int* __restrict__ deg_i, int E)
{
    int i = blockIdx.x * 256 + threadIdx.x;
    if (i < E) atomicAdd(deg_i + dst[i], 1);
}

__global__ __launch_bounds__(256) void scanA_kernel(
    const int* __restrict__ deg_i, int* __restrict__ pos,
    int* __restrict__ bsum, int N)
{
    __shared__ int s[256];
    const int tid = threadIdx.x;
    const int i = blockIdx.x * 256 + tid;
    int v = (i < N) ? deg_i[i] : 0;
    s[tid] = v;
    __syncthreads();
    #pragma unroll
    for (int off = 1; off < 256; off <<= 1) {
        int t = (tid >= off) ? s[tid - off] : 0;
        __syncthreads();
        s[tid] += t;
        __syncthreads();
    }
    if (i < N) pos[i] = s[tid] - v;          // block-local exclusive
    if (tid == 255) bsum[blockIdx.x] = s[255];
}

__global__ __launch_bounds__(256) void scanB_kernel(int* __restrict__ bsum, int NB)
{
    __shared__ int s[256];
    const int tid = threadIdx.x;
    int v = (tid < NB) ? bsum[tid] : 0;
    s[tid] = v;
    __syncthreads();
    #pragma unroll
    for (int off = 1; off < 256; off <<= 1) {
        int t = (tid >= off) ? s[tid - off] : 0;
        __syncthreads();
        s[tid] += t;
        __syncthreads();
    }
    if (tid < NB) bsum[tid] = s[tid] - v;    // exclusive
}

__global__ __launch_bounds__(256) void scanC_kernel(
    const int* __restrict__ pos, int* __restrict__ cursor,
    const int* __restrict__ bsum, int N)
{
    int i = blockIdx.x * 256 + threadIdx.x;
    if (i < N) cursor[i] = pos[i] + bsum[blockIdx.x];
}

__global__ __launch_bounds__(256) void scatter_kernel(
    const int* __restrict__ dst, int* __restrict__ cursor,
    int2* __restrict__ sorted_ed, int E)
{
    int i = blockIdx.x * 256 + threadIdx.x;
    if (i < E) {
        int dv = dst[i];
        int slot = atomicAdd(cursor + dv, 1);
        sorted_ed[slot] = make_int2(i, dv);
    }
}

// ---------------------------------------------------------------------------
// efp_seg: 128 dst-sorted edges per block (2 MFMA tiles), 4 waves.
// Per-lane sorted_ed loads (no barrier before gathers); ef-row gathers ->
// MFMA -> packed bf16 dwords stored BOTH to efp (natural layout, scattered)
// and to a bf16 LDS tile; one barrier; 256-thread parallel segment walk
// (16-row strip x dword-column each) -> f32 atomics into nb_sum.
// LDS ~17.4 KB -> 8 blocks/CU.
// ---------------------------------------------------------------------------
#define SEG_ROWS 128
__global__ __launch_bounds__(256) void efp_seg_kernel(
    const float* __restrict__ ef, const int2* __restrict__ sorted_ed,
    const ushort* __restrict__ Wt, ushort* __restrict__ efp,
    float* __restrict__ nb_sum, int E)
{
    __shared__ unsigned Slds[SEG_ROWS * 33];   // packed bf16 pairs, 16896 B
    __shared__ int dsts[SEG_ROWS];
    const int tid = threadIdx.x;
    const long s0 = (long)blockIdx.x * SEG_ROWS;

    const int w = tid >> 6, lane = tid & 63;
    const int lr = lane & 15, g = lane >> 4;
    const bool odd = lane & 1;

    // gather-row eids (per-lane, no LDS dependency)
    long gde[2];
    #pragma unroll
    for (int tt = 0; tt < 2; ++tt) {
        long s = s0 + 64 * tt + 16 * w + lr;
        if (s >= E) s = E - 1;
        gde[tt] = (long)sorted_ed[s].x;
    }
    // issue all ef gathers
    float4 va[2][4];
    #pragma unroll
    for (int tt = 0; tt < 2; ++tt) {
        const float4* ap = (const float4*)(ef + gde[tt] * D);
        va[tt][0] = ap[2 * g];     va[tt][1] = ap[2 * g + 1];
        va[tt][2] = ap[8 + 2 * g]; va[tt][3] = ap[8 + 2 * g + 1];
    }
    // store-row eids: int4 covers sorted_ed[rb] and [rb+1] (rb even)
    int rbl[2]; long seo[2][2];
    #pragma unroll
    for (int tt = 0; tt < 2; ++tt) {
        rbl[tt] = 64 * tt + 16 * w + 4 * g + (odd ? 2 : 0);
        long s = s0 + rbl[tt];
        if (s > E - 2) s = (E - 2) & ~1L;
        int4 q = *(const int4*)&sorted_ed[s];
        seo[tt][0] = (long)q.x * D;
        seo[tt][1] = (long)q.z * D;
    }
    // dsts for the walk
    if (tid < SEG_ROWS) {
        long s = s0 + tid;
        dsts[tid] = (s < E) ? sorted_ed[s].y : -1;
    }

    // B fragments (L1-resident)
    short8 bf0[4], bf1[4];
    #pragma unroll
    for (int t = 0; t < 4; ++t) {
        bf0[t] = *(const short8*)&Wt[(16 * t + lr) * D + 8 * g];
        bf1[t] = *(const short8*)&Wt[(16 * t + lr) * D + 32 + 8 * g];
    }

    #pragma unroll
    for (int tt = 0; tt < 2; ++tt) {
        short8 a0 = pack8(va[tt][0], va[tt][1]);
        short8 a1 = pack8(va[tt][2], va[tt][3]);
        f32x4 acc[4];
        #pragma unroll
        for (int t = 0; t < 4; ++t) {
            f32x4 z = {0.f, 0.f, 0.f, 0.f};
            z = __builtin_amdgcn_mfma_f32_16x16x32_bf16(a0, bf0[t], z, 0, 0, 0);
            z = __builtin_amdgcn_mfma_f32_16x16x32_bf16(a1, bf1[t], z, 0, 0, 0);
            acc[t] = z;
        }

        const int rb = rbl[tt];
        long sl0 = s0 + rb, sl1 = s0 + rb + 1;
        #pragma unroll
        for (int t = 0; t < 4; ++t) {
            float p0 = __shfl_xor(acc[t][0], 1, 64);
            float p1 = __shfl_xor(acc[t][1], 1, 64);
            float p2 = __shfl_xor(acc[t][2], 1, 64);
            float p3 = __shfl_xor(acc[t][3], 1, 64);
            float lo0, hi0, lo1, hi1;
            if (odd) { lo0 = p2; hi0 = acc[t][2]; lo1 = p3; hi1 = acc[t][3]; }
            else     { lo0 = acc[t][0]; hi0 = p0; lo1 = acc[t][1]; hi1 = p1; }
            int cbase = 16 * t + (lr & ~1);
            int dc = cbase >> 1;
            unsigned dw0 = ((unsigned)f2b(hi0) << 16) | (unsigned)f2b(lo0);
            unsigned dw1 = ((unsigned)f2b(hi1) << 16) | (unsigned)f2b(lo1);
            if (sl0 < E) *(unsigned*)(efp + seo[tt][0] + cbase) = dw0;
            if (sl1 < E) *(unsigned*)(efp + seo[tt][1] + cbase) = dw1;
            Slds[rb * 33 + dc]       = dw0;
            Slds[(rb + 1) * 33 + dc] = dw1;
        }
    }
    __syncthreads();

    // parallel segment walk: dword-col = tid&31 (2 f32 cols), strip of 16 rows.
    {
        const int dwc = tid & 31;
        const int r0 = (tid >> 5) * 16;
        float seg0 = 0.f, seg1 = 0.f;
        int cur = dsts[r0];
        #pragma unroll 4
        for (int r = r0; r < r0 + 16; ++r) {
            int dv = dsts[r];
            unsigned u = Slds[r * 33 + dwc];
            if (dv != cur) {
                if (cur >= 0) {
                    atomicAdd(nb_sum + (long)cur * D + 2 * dwc, seg0);
                    atomicAdd(nb_sum + (long)cur * D + 2 * dwc + 1, seg1);
                }
                seg0 = seg1 = 0.f;
                cur = dv;
            }
            seg0 += b2f((ushort)(u & 0xffff));
            seg1 += b2f((ushort)(u >> 16));
        }
        if (cur >= 0) {
            atomicAdd(nb_sum + (long)cur * D + 2 * dwc, seg0);
            atomicAdd(nb_sum + (long)cur * D + 2 * dwc + 1, seg1);
        }
    }
}

// ---------------------------------------------------------------------------
// ndp_lite: ndp_b[n] = bf16( nb_sum[n]/max(deg,1) + nfp[n] ).  Elementwise.
// ---------------------------------------------------------------------------
__global__ __launch_bounds__(256) void ndp_lite_kernel(
    const float* __restrict__ nb_sum, const int* __restrict__ deg_i,
    const ushort* __restrict__ nfp_b, ushort* __restrict__ ndp_b, int N)
{
    long i = (long)blockIdx.x * 256 + threadIdx.x;   // group = (node, col-block)
    long node = i >> 3;
    int cb = (int)(i & 7);
    if (node >= N) return;
    float inv = 1.0f / fmaxf((float)deg_i[node], 1.0f);
    const float4* sp = (const float4*)(nb_sum + node * D + cb * 8);
    float4 x0 = sp[0], x1 = sp[1];
    short8 np = *(const short8*)(nfp_b + node * D + cb * 8);
    short8 r;
    r[0] = (short)f2b(x0.x * inv + b2f((ushort)np[0]));
    r[1] = (short)f2b(x0.y * inv + b2f((ushort)np[1]));
    r[2] = (short)f2b(x0.z * inv + b2f((ushort)np[2]));
    r[3] = (short)f2b(x0.w * inv + b2f((ushort)np[3]));
    r[4] = (short)f2b(x1.x * inv + b2f((ushort)np[4]));
    r[5] = (short)f2b(x1.y * inv + b2f((ushort)np[5]));
    r[6] = (short)f2b(x1.z * inv + b2f((ushort)np[6]));
    r[7] = (short)f2b(x1.w * inv + b2f((ushort)np[7]));
    *(short8*)(ndp_b + node * D + cb * 8) = r;
}

// ---------------------------------------------------------------------------
// final: ef_out = relu(efp + ndp[dst] + nfp[src] + bias2). Pure elementwise.
// 4 threads per edge, 16 cols each.
// ---------------------------------------------------------------------------
__global__ __launch_bounds__(256) void final_kernel(
    const ushort* __restrict__ efp, const int* __restrict__ src,
    const int* __restrict__ dst, const ushort* __restrict__ ndp_b,
    const ushort* __restrict__ nfp_b, const float* __restrict__ bias2,
    float* __restrict__ out, int E)
{
    long idx = (long)blockIdx.x * 256 + threadIdx.x;
    long e = idx >> 2;
    int q = (int)(idx & 3);
    if (e >= E) return;
    int dv = dst[e], sv = src[e];
    const short8* ep = (const short8*)(efp + e * D + q * 16);
    const short8* np = (const short8*)(ndp_b + (long)dv * D + q * 16);
    const short8* sp = (const short8*)(nfp_b + (long)sv * D + q * 16);
    short8 e0 = ep[0], e1 = ep[1];
    short8 n0 = np[0], n1 = np[1];
    short8 s0 = sp[0], s1 = sp[1];
    const float4* bp = (const float4*)(bias2 + q * 16);
    float4 b0 = bp[0], b1 = bp[1], b2 = bp[2], b3 = bp[3];

    float r[16];
    #pragma unroll
    for (int j = 0; j < 8; ++j) {
        r[j]     = b2f((ushort)e0[j]) + b2f((ushort)n0[j]) + b2f((ushort)s0[j]);
        r[8 + j] = b2f((ushort)e1[j]) + b2f((ushort)n1[j]) + b2f((ushort)s1[j]);
    }
    float4* op = (float4*)(out + e * D + q * 16);
    op[0] = make_float4(fmaxf(r[0] + b0.x, 0.f), fmaxf(r[1] + b0.y, 0.f),
                        fmaxf(r[2] + b0.z, 0.f), fmaxf(r[3] + b0.w, 0.f));
    op[1] = make_float4(fmaxf(r[4] + b1.x, 0.f), fmaxf(r[5] + b1.y, 0.f),
                        fmaxf(r[6] + b1.z, 0.f), fmaxf(r[7] + b1.w, 0.f));
    op[2] = make_float4(fmaxf(r[8] + b2.x, 0.f), fmaxf(r[9] + b2.y, 0.f),
                        fmaxf(r[10] + b2.z, 0.f), fmaxf(r[11] + b2.w, 0.f));
    op[3] = make_float4(fmaxf(r[12] + b3.x, 0.f), fmaxf(r[13] + b3.y, 0.f),
                        fmaxf(r[14] + b3.z, 0.f), fmaxf(r[15] + b3.w, 0.f));
}

// ---------------------------------------------------------------------------
extern "C" void kernel_launch(void* const* d_in, const int* in_sizes, int n_in,
                              void* d_out, int out_size, void* d_ws, size_t ws_size,
                              hipStream_t stream) {
    const float* nf        = (const float*)d_in[0];
    const float* ef        = (const float*)d_in[1];
    const int*   src       = (const int*)d_in[2];
    const int*   dst       = (const int*)d_in[3];
    const float* W_node    = (const float*)d_in[4];
    const float* W_edge    = (const float*)d_in[5];
    const float* bias_node = (const float*)d_in[6];
    const float* bias_edge = (const float*)d_in[7];
    const float* W_dense   = (const float*)d_in[8];
    const float* b_dense   = (const float*)d_in[9];

    const int N = in_sizes[0] / D;
    const int E = in_sizes[1] / D;
    const int NB = (N + 255) / 256;

    float* nf_out = (float*)d_out;
    float* ef_out = (float*)d_out + (size_t)N * D;

    // ws layout: [zeroed: deg_i, nb_sum] then the rest
    char* p = (char*)d_ws;
    int*    deg_i    = (int*)p;     p += (size_t)N * 4;           // zeroed
    float*  nb_sum   = (float*)p;   p += (size_t)N * D * 4;       // zeroed, 12.8 MB
    size_t  zbytes   = (size_t)(p - (char*)d_ws);
    int*    pos      = (int*)p;     p += (size_t)N * 4;
    int*    cursor   = (int*)p;     p += (size_t)N * 4;
    int*    bsum     = (int*)p;     p += 256 * 4;
    int2*   sorted_ed= (int2*)p;    p += (size_t)E * 8;           // 6.4 MB
    ushort* nfp_b    = (ushort*)p;  p += (size_t)N * D * 2;
    ushort* ndp_b    = (ushort*)p;  p += (size_t)N * D * 2;
    ushort* Wcomb_b  = (ushort*)p;  p += D * D * 2;
    float*  bias2    = (float*)p;   p += 256;
    ushort* efp      = (ushort*)p;  /* E*D*2 = 102.4 MB */

    hipMemsetAsync(d_ws, 0, zbytes, stream);

    setup_kernel<<<1, 256, 0, stream>>>(W_edge, W_dense, b_dense, bias_edge,
                                        Wcomb_b, bias2);
    node_proj_kernel<<<(N + 15) / 16, 256, 0, stream>>>(nf, W_node, bias_node,
                                                        W_dense + D * D, nf_out, nfp_b, N);
    hist_kernel<<<(E + 255) / 256, 256, 0, stream>>>(dst, deg_i, E);
    scanA_kernel<<<NB, 256, 0, stream>>>(deg_i, pos, bsum, N);
    scanB_kernel<<<1, 256, 0, stream>>>(bsum, NB);
    scanC_kernel<<<NB, 256, 0, stream>>>(pos, cursor, bsum, N);
    scatter_kernel<<<(E + 255) / 256, 256, 0, stream>>>(dst, cursor, sorted_ed, E);
    efp_seg_kernel<<<(E + SEG_ROWS - 1) / SEG_ROWS, 256, 0, stream>>>(
        ef, sorted_ed, Wcomb_b, efp, nb_sum, E);
    ndp_lite_kernel<<<(int)(((size_t)N * 8 + 255) / 256), 256, 0, stream>>>(
        nb_sum, deg_i, nfp_b, ndp_b, N);
    final_kernel<<<(int)(((size_t)E * 4 + 255) / 256), 256, 0, stream>>>(
        efp, src, dst, ndp_b, nfp_b, bias2, ef_out, E);
}

// Round 9
// 399.224 us; speedup vs baseline: 1.0015x; 1.0015x over previous
//
#include <hip/hip_runtime.h>

#define D 64

typedef __attribute__((ext_vector_type(8))) short short8;
typedef __attribute__((ext_vector_type(4))) float f32x4;

__device__ __forceinline__ ushort f2b(float f) {
    union { float f; unsigned u; } x; x.f = f;
    unsigned r = x.u + 0x7FFFu + ((x.u >> 16) & 1u);   // RNE to bf16
    return (ushort)(r >> 16);
}
__device__ __forceinline__ float b2f(ushort u) {
    union { float f; unsigned u; } x; x.u = ((unsigned)u) << 16;
    return x.f;
}
__device__ __forceinline__ short8 pack8(float4 a, float4 b) {
    short8 r;
    r[0] = (short)f2b(a.x); r[1] = (short)f2b(a.y); r[2] = (short)f2b(a.z); r[3] = (short)f2b(a.w);
    r[4] = (short)f2b(b.x); r[5] = (short)f2b(b.y); r[6] = (short)f2b(b.z); r[7] = (short)f2b(b.w);
    return r;
}

// ---------------------------------------------------------------------------
// Setup: Wcomb_b[n*64+k] = bf16( (W_edge @ W_dense[0:64])[k][n] ),
// bias2 = b_dense + bias_edge.
// ---------------------------------------------------------------------------
__global__ __launch_bounds__(256) void setup_kernel(
    const float* __restrict__ W_edge, const float* __restrict__ W_dense,
    const float* __restrict__ b_dense, const float* __restrict__ bias_edge,
    ushort* __restrict__ Wcomb_b, float* __restrict__ bias2)
{
    const int tid = threadIdx.x;
    for (int idx = tid; idx < D * D; idx += 256) {
        int k = idx >> 6, n = idx & 63;
        float s = 0.f;
        #pragma unroll 8
        for (int j = 0; j < D; ++j)
            s = fmaf(W_edge[k * D + j], W_dense[j * D + n], s);
        Wcomb_b[n * D + k] = f2b(s);   // B-fragment layout [n][k]
    }
    if (tid < D) bias2[tid] = b_dense[tid] + bias_edge[tid];
}

// ---------------------------------------------------------------------------
// Kernel 1 (fused): nf_out = relu(nf @ W_node + bias_node)  (f32, exact)
//                   nfp_b  = bf16( nf_out @ (0.5 * W_dense[64:128]) )
// ---------------------------------------------------------------------------
__global__ __launch_bounds__(256) void node_proj_kernel(
    const float* __restrict__ nf, const float* __restrict__ Wn,
    const float* __restrict__ bias, const float* __restrict__ Wd_bot,
    float* __restrict__ out, ushort* __restrict__ nfp_b, int N)
{
    constexpr int ROWS = 16;
    __shared__ float Ws[D * D];
    __shared__ float Wb[D * D];
    __shared__ float As[ROWS * D];
    __shared__ float Vs[ROWS * D];
    const int tid = threadIdx.x;
    const long row0 = (long)blockIdx.x * ROWS;

    #pragma unroll
    for (int i = tid; i < D * D / 4; i += 256) {
        ((float4*)Ws)[i] = ((const float4*)Wn)[i];
        float4 v = ((const float4*)Wd_bot)[i];
        ((float4*)Wb)[i] = make_float4(0.5f * v.x, 0.5f * v.y, 0.5f * v.z, 0.5f * v.w);
    }
    {
        int i = tid;  // ROWS*D/4 == 256
        long r = row0 + (i * 4) / D;
        ((float4*)As)[i] = (r < N) ? ((const float4*)nf)[row0 * D / 4 + i]
                                   : make_float4(0.f, 0.f, 0.f, 0.f);
    }
    __syncthreads();

    const int c = tid & 63;
    const float b = bias[c];
    for (int rr = tid >> 6; rr < ROWS; rr += 4) {
        float acc = 0.f;
        #pragma unroll
        for (int k = 0; k < D; ++k)
            acc = fmaf(As[rr * D + k], Ws[k * D + c], acc);
        float v = fmaxf(acc + b, 0.f);
        Vs[rr * D + c] = v;
        long r = row0 + rr;
        if (r < N) out[r * D + c] = v;
    }
    __syncthreads();
    for (int rr = tid >> 6; rr < ROWS; rr += 4) {
        float acc = 0.f;
        #pragma unroll
        for (int k = 0; k < D; ++k)
            acc = fmaf(Vs[rr * D + k], Wb[k * D + c], acc);
        long r = row0 + rr;
        if (r < N) nfp_b[r * D + c] = f2b(acc);
    }
}

// ---------------------------------------------------------------------------
// Counting sort of edges by dst: hist -> scan (3 stages) -> scatter (eid,dst)
// ---------------------------------------------------------------------------
__global__ __launch_bounds__(256) void hist_kernel(
    const int* __restrict__ dst, int* __restrict__ deg_i, int E)
{
    int i = blockIdx.x * 256 + threadIdx.x;
    if (i < E) atomicAdd(deg_i + dst[i], 1);
}

__global__ __launch_bounds__(256) void scanA_kernel(
    const int* __restrict__ deg_i, int* __restrict__ pos,
    int* __restrict__ bsum, int N)
{
    __shared__ int s[256];
    const int tid = threadIdx.x;
    const int i = blockIdx.x * 256 + tid;
    int v = (i < N) ? deg_i[i] : 0;
    s[tid] = v;
    __syncthreads();
    #pragma unroll
    for (int off = 1; off < 256; off <<= 1) {
        int t = (tid >= off) ? s[tid - off] : 0;
        __syncthreads();
        s[tid] += t;
        __syncthreads();
    }
    if (i < N) pos[i] = s[tid] - v;          // block-local exclusive
    if (tid == 255) bsum[blockIdx.x] = s[255];
}

__global__ __launch_bounds__(256) void scanB_kernel(int* __restrict__ bsum, int NB)
{
    __shared__ int s[256];
    const int tid = threadIdx.x;
    int v = (tid < NB) ? bsum[tid] : 0;
    s[tid] = v;
    __syncthreads();
    #pragma unroll
    for (int off = 1; off < 256; off <<= 1) {
        int t = (tid >= off) ? s[tid - off] : 0;
        __syncthreads();
        s[tid] += t;
        __syncthreads();
    }
    if (tid < NB) bsum[tid] = s[tid] - v;    // exclusive
}

__global__ __launch_bounds__(256) void scanC_kernel(
    const int* __restrict__ pos, int* __restrict__ cursor,
    const int* __restrict__ bsum, int N)
{
    int i = blockIdx.x * 256 + threadIdx.x;
    if (i < N) cursor[i] = pos[i] + bsum[blockIdx.x];
}

__global__ __launch_bounds__(256) void scatter_kernel(
    const int* __restrict__ dst, int* __restrict__ cursor,
    int2* __restrict__ sorted_ed, int E)
{
    int i = blockIdx.x * 256 + threadIdx.x;
    if (i < E) {
        int dv = dst[i];
        int slot = atomicAdd(cursor + dv, 1);
        sorted_ed[slot] = make_int2(i, dv);
    }
}

// ---------------------------------------------------------------------------
// efp_seg: 128 dst-sorted edges per block (2 MFMA tiles), 4 waves.
// Per-lane sorted_ed loads (no barrier before gathers); ef-row gathers ->
// MFMA -> packed bf16 dwords stored BOTH to efp (natural layout, scattered)
// and to a bf16 LDS tile; one barrier; 256-thread parallel segment walk
// (16-row strip x dword-column each) -> f32 atomics into nb_sum.
// LDS ~17.4 KB -> 8 blocks/CU.
// ---------------------------------------------------------------------------
#define SEG_ROWS 128
__global__ __launch_bounds__(256) void efp_seg_kernel(
    const float* __restrict__ ef, const int2* __restrict__ sorted_ed,
    const ushort* __restrict__ Wt, ushort* __restrict__ efp,
    float* __restrict__ nb_sum, int E)
{
    __shared__ unsigned Slds[SEG_ROWS * 33];   // packed bf16 pairs, 16896 B
    __shared__ int dsts[SEG_ROWS];
    const int tid = threadIdx.x;
    const long s0 = (long)blockIdx.x * SEG_ROWS;

    const int w = tid >> 6, lane = tid & 63;
    const int lr = lane & 15, g = lane >> 4;
    const bool odd = lane & 1;

    // gather-row eids (per-lane, no LDS dependency)
    long gde[2];
    #pragma unroll
    for (int tt = 0; tt < 2; ++tt) {
        long s = s0 + 64 * tt + 16 * w + lr;
        if (s >= E) s = E - 1;
        gde[tt] = (long)sorted_ed[s].x;
    }
    // issue all ef gathers
    float4 va[2][4];
    #pragma unroll
    for (int tt = 0; tt < 2; ++tt) {
        const float4* ap = (const float4*)(ef + gde[tt] * D);
        va[tt][0] = ap[2 * g];     va[tt][1] = ap[2 * g + 1];
        va[tt][2] = ap[8 + 2 * g]; va[tt][3] = ap[8 + 2 * g + 1];
    }
    // store-row eids: int4 covers sorted_ed[rb] and [rb+1] (rb even)
    int rbl[2]; long seo[2][2];
    #pragma unroll
    for (int tt = 0; tt < 2; ++tt) {
        rbl[tt] = 64 * tt + 16 * w + 4 * g + (odd ? 2 : 0);
        long s = s0 + rbl[tt];
        if (s > E - 2) s = (E - 2) & ~1L;
        int4 q = *(const int4*)&sorted_ed[s];
        seo[tt][0] = (long)q.x * D;
        seo[tt][1] = (long)q.z * D;
    }
    // dsts for the walk
    if (tid < SEG_ROWS) {
        long s = s0 + tid;
        dsts[tid] = (s < E) ? sorted_ed[s].y : -1;
    }

    // B fragments (L1-resident)
    short8 bf0[4], bf1[4];
    #pragma unroll
    for (int t = 0; t < 4; ++t) {
        bf0[t] = *(const short8*)&Wt[(16 * t + lr) * D + 8 * g];
        bf1[t] = *(const short8*)&Wt[(16 * t + lr) * D + 32 + 8 * g];
    }

    #pragma unroll
    for (int tt = 0; tt < 2; ++tt) {
        short8 a0 = pack8(va[tt][0], va[tt][1]);
        short8 a1 = pack8(va[tt][2], va[tt][3]);
        f32x4 acc[4];
        #pragma unroll
        for (int t = 0; t < 4; ++t) {
            f32x4 z = {0.f, 0.f, 0.f, 0.f};
            z = __builtin_amdgcn_mfma_f32_16x16x32_bf16(a0, bf0[t], z, 0, 0, 0);
            z = __builtin_amdgcn_mfma_f32_16x16x32_bf16(a1, bf1[t], z, 0, 0, 0);
            acc[t] = z;
        }

        const int rb = rbl[tt];
        long sl0 = s0 + rb, sl1 = s0 + rb + 1;
        #pragma unroll
        for (int t = 0; t < 4; ++t) {
            float p0 = __shfl_xor(acc[t][0], 1, 64);
            float p1 = __shfl_xor(acc[t][1], 1, 64);
            float p2 = __shfl_xor(acc[t][2], 1, 64);
            float p3 = __shfl_xor(acc[t][3], 1, 64);
            float lo0, hi0, lo1, hi1;
            if (odd) { lo0 = p2; hi0 = acc[t][2]; lo1 = p3; hi1 = acc[t][3]; }
            else     { lo0 = acc[t][0]; hi0 = p0; lo1 = acc[t][1]; hi1 = p1; }
            int cbase = 16 * t + (lr & ~1);
            int dc = cbase >> 1;
            unsigned dw0 = ((unsigned)f2b(hi0) << 16) | (unsigned)f2b(lo0);
            unsigned dw1 = ((unsigned)f2b(hi1) << 16) | (unsigned)f2b(lo1);
            if (sl0 < E) *(unsigned*)(efp + seo[tt][0] + cbase) = dw0;
            if (sl1 < E) *(unsigned*)(efp + seo[tt][1] + cbase) = dw1;
            Slds[rb * 33 + dc]       = dw0;
            Slds[(rb + 1) * 33 + dc] = dw1;
        }
    }
    __syncthreads();

    // parallel segment walk: dword-col = tid&31 (2 f32 cols), strip of 16 rows.
    {
        const int dwc = tid & 31;
        const int r0 = (tid >> 5) * 16;
        float seg0 = 0.f, seg1 = 0.f;
        int cur = dsts[r0];
        #pragma unroll 4
        for (int r = r0; r < r0 + 16; ++r) {
            int dv = dsts[r];
            unsigned u = Slds[r * 33 + dwc];
            if (dv != cur) {
                if (cur >= 0) {
                    atomicAdd(nb_sum + (long)cur * D + 2 * dwc, seg0);
                    atomicAdd(nb_sum + (long)cur * D + 2 * dwc + 1, seg1);
                }
                seg0 = seg1 = 0.f;
                cur = dv;
            }
            seg0 += b2f((ushort)(u & 0xffff));
            seg1 += b2f((ushort)(u >> 16));
        }
        if (cur >= 0) {
            atomicAdd(nb_sum + (long)cur * D + 2 * dwc, seg0);
            atomicAdd(nb_sum + (long)cur * D + 2 * dwc + 1, seg1);
        }
    }
}

// ---------------------------------------------------------------------------
// ndp_lite: ndp_b[n] = bf16( nb_sum[n]/max(deg,1) + nfp[n] ).  Elementwise.
// ---------------------------------------------------------------------------
__global__ __launch_bounds__(256) void ndp_lite_kernel(
    const float* __restrict__ nb_sum, const int* __restrict__ deg_i,
    const ushort* __restrict__ nfp_b, ushort* __restrict__ ndp_b, int N)
{
    long i = (long)blockIdx.x * 256 + threadIdx.x;   // group = (node, col-block)
    long node = i >> 3;
    int cb = (int)(i & 7);
    if (node >= N) return;
    float inv = 1.0f / fmaxf((float)deg_i[node], 1.0f);
    const float4* sp = (const float4*)(nb_sum + node * D + cb * 8);
    float4 x0 = sp[0], x1 = sp[1];
    short8 np = *(const short8*)(nfp_b + node * D + cb * 8);
    short8 r;
    r[0] = (short)f2b(x0.x * inv + b2f((ushort)np[0]));
    r[1] = (short)f2b(x0.y * inv + b2f((ushort)np[1]));
    r[2] = (short)f2b(x0.z * inv + b2f((ushort)np[2]));
    r[3] = (short)f2b(x0.w * inv + b2f((ushort)np[3]));
    r[4] = (short)f2b(x1.x * inv + b2f((ushort)np[4]));
    r[5] = (short)f2b(x1.y * inv + b2f((ushort)np[5]));
    r[6] = (short)f2b(x1.z * inv + b2f((ushort)np[6]));
    r[7] = (short)f2b(x1.w * inv + b2f((ushort)np[7]));
    *(short8*)(ndp_b + node * D + cb * 8) = r;
}

// ---------------------------------------------------------------------------
// final: ef_out = relu(efp + ndp[dst] + nfp[src] + bias2). Pure elementwise.
// 4 threads per edge, 16 cols each.
// ---------------------------------------------------------------------------
__global__ __launch_bounds__(256) void final_kernel(
    const ushort* __restrict__ efp, const int* __restrict__ src,
    const int* __restrict__ dst, const ushort* __restrict__ ndp_b,
    const ushort* __restrict__ nfp_b, const float* __restrict__ bias2,
    float* __restrict__ out, int E)
{
    long idx = (long)blockIdx.x * 256 + threadIdx.x;
    long e = idx >> 2;
    int q = (int)(idx & 3);
    if (e >= E) return;
    int dv = dst[e], sv = src[e];
    const short8* ep = (const short8*)(efp + e * D + q * 16);
    const short8* np = (const short8*)(ndp_b + (long)dv * D + q * 16);
    const short8* sp = (const short8*)(nfp_b + (long)sv * D + q * 16);
    short8 e0 = ep[0], e1 = ep[1];
    short8 n0 = np[0], n1 = np[1];
    short8 s0 = sp[0], s1 = sp[1];
    const float4* bp = (const float4*)(bias2 + q * 16);
    float4 b0 = bp[0], b1 = bp[1], b2 = bp[2], b3 = bp[3];

    float r[16];
    #pragma unroll
    for (int j = 0; j < 8; ++j) {
        r[j]     = b2f((ushort)e0[j]) + b2f((ushort)n0[j]) + b2f((ushort)s0[j]);
        r[8 + j] = b2f((ushort)e1[j]) + b2f((ushort)n1[j]) + b2f((ushort)s1[j]);
    }
    float4* op = (float4*)(out + e * D + q * 16);
    op[0] = make_float4(fmaxf(r[0] + b0.x, 0.f), fmaxf(r[1] + b0.y, 0.f),
                        fmaxf(r[2] + b0.z, 0.f), fmaxf(r[3] + b0.w, 0.f));
    op[1] = make_float4(fmaxf(r[4] + b1.x, 0.f), fmaxf(r[5] + b1.y, 0.f),
                        fmaxf(r[6] + b1.z, 0.f), fmaxf(r[7] + b1.w, 0.f));
    op[2] = make_float4(fmaxf(r[8] + b2.x, 0.f), fmaxf(r[9] + b2.y, 0.f),
                        fmaxf(r[10] + b2.z, 0.f), fmaxf(r[11] + b2.w, 0.f));
    op[3] = make_float4(fmaxf(r[12] + b3.x, 0.f), fmaxf(r[13] + b3.y, 0.f),
                        fmaxf(r[14] + b3.z, 0.f), fmaxf(r[15] + b3.w, 0.f));
}

// ---------------------------------------------------------------------------
extern "C" void kernel_launch(void* const* d_in, const int* in_sizes, int n_in,
                              void* d_out, int out_size, void* d_ws, size_t ws_size,
                              hipStream_t stream) {
    const float* nf        = (const float*)d_in[0];
    const float* ef        = (const float*)d_in[1];
    const int*   src       = (const int*)d_in[2];
    const int*   dst       = (const int*)d_in[3];
    const float* W_node    = (const float*)d_in[4];
    const float* W_edge    = (const float*)d_in[5];
    const float* bias_node = (const float*)d_in[6];
    const float* bias_edge = (const float*)d_in[7];
    const float* W_dense   = (const float*)d_in[8];
    const float* b_dense   = (const float*)d_in[9];

    const int N = in_sizes[0] / D;
    const int E = in_sizes[1] / D;
    const int NB = (N + 255) / 256;

    float* nf_out = (float*)d_out;
    float* ef_out = (float*)d_out + (size_t)N * D;

    // ws layout: [zeroed: deg_i, nb_sum] then the rest
    char* p = (char*)d_ws;
    int*    deg_i    = (int*)p;     p += (size_t)N * 4;           // zeroed
    float*  nb_sum   = (float*)p;   p += (size_t)N * D * 4;       // zeroed, 12.8 MB
    size_t  zbytes   = (size_t)(p - (char*)d_ws);
    int*    pos      = (int*)p;     p += (size_t)N * 4;
    int*    cursor   = (int*)p;     p += (size_t)N * 4;
    int*    bsum     = (int*)p;     p += 256 * 4;
    int2*   sorted_ed= (int2*)p;    p += (size_t)E * 8;           // 6.4 MB
    ushort* nfp_b    = (ushort*)p;  p += (size_t)N * D * 2;
    ushort* ndp_b    = (ushort*)p;  p += (size_t)N * D * 2;
    ushort* Wcomb_b  = (ushort*)p;  p += D * D * 2;
    float*  bias2    = (float*)p;   p += 256;
    ushort* efp      = (ushort*)p;  /* E*D*2 = 102.4 MB */

    hipMemsetAsync(d_ws, 0, zbytes, stream);

    setup_kernel<<<1, 256, 0, stream>>>(W_edge, W_dense, b_dense, bias_edge,
                                        Wcomb_b, bias2);
    node_proj_kernel<<<(N + 15) / 16, 256, 0, stream>>>(nf, W_node, bias_node,
                                                        W_dense + D * D, nf_out, nfp_b, N);
    hist_kernel<<<(E + 255) / 256, 256, 0, stream>>>(dst, deg_i, E);
    scanA_kernel<<<NB, 256, 0, stream>>>(deg_i, pos, bsum, N);
    scanB_kernel<<<1, 256, 0, stream>>>(bsum, NB);
    scanC_kernel<<<NB, 256, 0, stream>>>(pos, cursor, bsum, N);
    scatter_kernel<<<(E + 255) / 256, 256, 0, stream>>>(dst, cursor, sorted_ed, E);
    efp_seg_kernel<<<(E + SEG_ROWS - 1) / SEG_ROWS, 256, 0, stream>>>(
        ef, sorted_ed, Wcomb_b, efp, nb_sum, E);
    ndp_lite_kernel<<<(int)(((size_t)N * 8 + 255) / 256), 256, 0, stream>>>(
        nb_sum, deg_i, nfp_b, ndp_b, N);
    final_kernel<<<(int)(((size_t)E * 4 + 255) / 256), 256, 0, stream>>>(
        efp, src, dst, ndp_b, nfp_b, bias2, ef_out, E);
}